// Round 8
// baseline (49508.563 us; speedup 1.0000x reference)
//
#include <hip/hip_runtime.h>
#include <math.h>

#define NBLK   64
#define BS     256
#define NSTATE 17
#define NH     256
#define NX     273      // NH + NSTATE
#define WID    1024
#define NT     64
#define NSUB   8
#define ROWS_H (WID/NBLK)   // 16 rows per block for 1024-wide layers
#define ROWS_L (NH/NBLK)    // 4 rows per block for the 256-wide output layer

typedef unsigned int uint;

__device__ __forceinline__ float softplus_f(float v) {
    return fmaxf(v, 0.f) + log1pf(expf(-fabsf(v)));
}

// ---- AGENT-scope (coherence-point) scalar ops: proven codegen from r2/r3 ----
__device__ __forceinline__ uint ldS(const uint* p) {
    return __hip_atomic_load(p, __ATOMIC_RELAXED, __HIP_MEMORY_SCOPE_AGENT);
}
__device__ __forceinline__ void stS(uint* p, uint v) {
    __hip_atomic_store(p, v, __ATOMIC_RELAXED, __HIP_MEMORY_SCOPE_AGENT);
}
__device__ __forceinline__ float ldD(const float* p) {
    return __hip_atomic_load(p, __ATOMIC_RELAXED, __HIP_MEMORY_SCOPE_AGENT);
}
__device__ __forceinline__ void stD(float* p, float v) {
    __hip_atomic_store(p, v, __ATOMIC_RELAXED, __HIP_MEMORY_SCOPE_AGENT);
}

// r8 protocol: payload = plain AGENT floats; per-producer summary word S[j]=R
// published AFTER __syncthreads() (drains vmcnt -> data complete at the
// coherence point before the summary store issues). Consumers poll ONLY the
// 64 summary words (16x less poll traffic than r3's 1024 tagged words), then
// read their payload slice once.
__device__ __forceinline__ void publish(uint* S, int blk, uint R, int t) {
    __syncthreads();                 // all lanes' payload stores drained
    if (t == 0) stS(&S[blk], R);
}

// 1024-word buffer: thread t waits on producer j=t&63, then copies 4 floats
// of j's 16-float slice (sub=t>>6) into LDS.
__device__ __forceinline__ void poll_z(const uint* __restrict__ S,
                                       const float* __restrict__ z,
                                       uint R, float* __restrict__ z_s, int t) {
    const int j = t & 63, sub = t >> 6;
    while (ldS(S + j) != R) {}
    __atomic_signal_fence(__ATOMIC_SEQ_CST);   // keep payload loads below poll
    const int base = j * 16 + sub * 4;
    #pragma unroll
    for (int i = 0; i < 4; i++) z_s[base + i] = ldD(z + base + i);
    __syncthreads();
}

extern "C" __global__ __launch_bounds__(BS, 1) void ode_kernel(
    const float* __restrict__ ts,   const float* __restrict__ W0,
    const float* __restrict__ b0,   const float* __restrict__ Wh,
    const float* __restrict__ bh,   const float* __restrict__ Wl,
    const float* __restrict__ bl,   const float* __restrict__ betaW,
    const float* __restrict__ betab,const float* __restrict__ hvec,
    const float* __restrict__ scale,const float* __restrict__ y0log,
    float* __restrict__ out,
    uint* SzA, uint* SzB, uint* Sdh, float* zA, float* zB, float* dhb)
{
    const int t   = threadIdx.x;
    const int blk = blockIdx.x;

    __shared__ float y_s[NX];
    __shared__ float yn_s[NX];
    __shared__ float x_s[NX];
    __shared__ float xm[NX];
    __shared__ float k_s[NX];
    __shared__ __align__(16) float z_s[WID];
    __shared__ float red[4];
    __shared__ float dt_sh;

    const float scale0 = scale[0];
    const float betab0 = betab[0];
    uint R = 0;   // global leg counter; identical sequence on all blocks

    // ---- y0 = [softmax(y0_log), hvec] ----
    if (t < NSTATE) {
        float m = -1e30f;
        for (int j = 0; j < NSTATE; j++) m = fmaxf(m, y0log[j]);
        float ssum = 0.f;
        for (int j = 0; j < NSTATE; j++) ssum += expf(y0log[j] - m);
        y_s[t] = expf(y0log[t] - m) / ssum;
    }
    y_s[NSTATE + t] = hvec[t];
    __syncthreads();

    if (blk == 0) {
        if (t < NSTATE) out[t] = y_s[t];
        out[NT * NSTATE + t] = y_s[NSTATE + t];
    }

    const float c_xi = 13.f / 12.f, c_mu = 0.041f / 12.f, c_sig = 91.f / 12.f,
                c_nu = 36.f / 12.f, c_gam = 1.8f / 12.f;

    const int laneH = t & 15;
    const int growH = blk * ROWS_H + (t >> 4);
    const int laneL = t & 63;
    const int growL = blk * ROWS_L + (t >> 6);

    for (int iv = 0; iv < NT - 1; iv++) {
        if (t == 0) dt_sh = (ts[iv + 1] - ts[iv]) * (1.f / NSUB);
        __syncthreads();
        const float dt = dt_sh;

        for (int sub = 0; sub < NSUB; sub++) {
            for (int i = t; i < NX; i += BS) yn_s[i] = y_s[i];

            for (int s = 0; s < 4; s++) {
                const float a = (s == 0) ? 0.f : ((s == 3) ? 1.f : 0.5f);
                const float w = ((s == 0) || (s == 3)) ? dt * (1.f / 6.f) : dt * (1.f / 3.f);

                // ---- stage input x = y + a*dt*k_prev ----
                if (s == 0) { for (int i = t; i < NX; i += BS) x_s[i] = y_s[i]; }
                else        { for (int i = t; i < NX; i += BS) x_s[i] = y_s[i] + a * dt * k_s[i]; }
                __syncthreads();

                // ---- MLP input reorder + beta head partial ----
                xm[t] = x_s[NSTATE + t];
                if (t < NSTATE) xm[NH + t] = x_s[t];
                float p = betaW[t] * x_s[NSTATE + t];
                #pragma unroll
                for (int m = 1; m < 64; m <<= 1) p += __shfl_xor(p, m, 64);
                if ((t & 63) == 0) red[t >> 6] = p;
                __syncthreads();

                // ---- dstate (redundant per block, thread 0) ----
                if (t == 0) {
                    float sd  = red[0] + red[1] + red[2] + red[3] + betab0;
                    float bb1 = 8.f / (1.f + expf(-sd)) + 25.f;
                    float bb2 = 0.5f * bb1, bb3 = 0.35f * bb1, bb4 = 0.25f * bb1;
                    float M  = x_s[0],  S1 = x_s[1],  E1 = x_s[2],  E2 = x_s[3];
                    float E3 = x_s[4],  E4 = x_s[5],  I1 = x_s[6],  I2 = x_s[7];
                    float I3 = x_s[8],  I4 = x_s[9],  R1 = x_s[10], R2 = x_s[11];
                    float R3 = x_s[12], R4 = x_s[13], S2 = x_s[14], S3 = x_s[15];
                    float S4 = x_s[16];
                    float I = I1 + I2 + I3 + I4, Rs = R1 + R2 + R3 + R4;
                    k_s[0]  = Rs * c_mu - (c_xi + c_mu) * M;
                    k_s[1]  = c_mu * (1.f - Rs) + c_xi * M - c_mu * S1 - bb1 * I * S1;
                    k_s[2]  = bb1 * I * S1 - (c_mu + c_sig) * E1;
                    k_s[3]  = bb2 * I * S2 - (c_mu + c_sig) * E2;
                    k_s[4]  = bb3 * I * S3 - (c_mu + c_sig) * E3;
                    k_s[5]  = bb4 * I * S4 - (c_mu + c_sig) * E4;
                    k_s[6]  = c_sig * E1 - (c_nu + c_mu) * I1;
                    k_s[7]  = c_sig * E2 - (c_nu + c_mu) * I2;
                    k_s[8]  = c_sig * E3 - (c_nu + c_mu) * I3;
                    k_s[9]  = c_sig * E4 - (c_nu + c_mu) * I4;
                    k_s[10] = c_nu * I1 - (c_mu + c_gam) * R1;
                    k_s[11] = c_nu * I2 - (c_mu + c_gam) * R2;
                    k_s[12] = c_nu * I3 - (c_mu + c_gam) * R3;
                    k_s[13] = c_nu * I4 - (c_mu + c_gam) * R4;
                    k_s[14] = c_gam * R1 - c_mu * S2 - bb2 * I * S2;
                    k_s[15] = c_gam * R2 - c_mu * S3 - bb3 * I * S3;
                    k_s[16] = c_gam * (R3 + R4) - c_mu * S4 - bb4 * I * S4;
                }
                __syncthreads();

                // ---- L0: 1024x273, 16 rows/block, 16 lanes/row (input local) ----
                {
                    const float* wr = W0 + (size_t)growH * NX;
                    float acc = 0.f;
                    for (int c = laneH; c < NX; c += 16) acc += wr[c] * xm[c];
                    #pragma unroll
                    for (int m = 1; m < 16; m <<= 1) acc += __shfl_xor(acc, m, 16);
                    if (laneH == 0) stD(&zA[growH], softplus_f(acc + b0[growH]));
                }
                ++R; publish(SzA, blk, R, t);

                // ---- hidden layers 1..3: 1024x1024; weights prefetch before poll ----
                for (int l = 0; l < 3; l++) {
                    const float* zin  = (l == 1) ? zB  : zA;
                    const uint*  Sin  = (l == 1) ? SzB : SzA;
                    float*       zout = (l == 1) ? zA  : zB;
                    uint*        Sout = (l == 1) ? SzA : SzB;

                    const float* wr = Wh + (size_t)l * WID * WID + (size_t)growH * WID;
                    float4 wv[16];
                    #pragma unroll
                    for (int i = 0; i < 16; i++)
                        wv[i] = *(const float4*)(wr + (laneH * 4 + i * 64));

                    poll_z(Sin, zin, R, z_s, t);

                    float acc = 0.f;
                    #pragma unroll
                    for (int i = 0; i < 16; i++) {
                        float4 zv = *(const float4*)(z_s + (laneH * 4 + i * 64));
                        acc += wv[i].x * zv.x + wv[i].y * zv.y + wv[i].z * zv.z + wv[i].w * zv.w;
                    }
                    #pragma unroll
                    for (int m = 1; m < 16; m <<= 1) acc += __shfl_xor(acc, m, 16);
                    if (laneH == 0)
                        stD(&zout[growH], softplus_f(acc + bh[l * WID + growH]));
                    ++R; publish(Sout, blk, R, t);
                }

                // ---- Wl: 256x1024, 4 rows/block; tanh epilogue (reads zB) ----
                {
                    const float* wr = Wl + (size_t)growL * WID;
                    float4 wv[4];
                    #pragma unroll
                    for (int i = 0; i < 4; i++)
                        wv[i] = *(const float4*)(wr + (laneL * 4 + i * 256));

                    poll_z(SzB, zB, R, z_s, t);

                    float acc = 0.f;
                    #pragma unroll
                    for (int i = 0; i < 4; i++) {
                        float4 zv = *(const float4*)(z_s + (laneL * 4 + i * 256));
                        acc += wv[i].x * zv.x + wv[i].y * zv.y + wv[i].z * zv.z + wv[i].w * zv.w;
                    }
                    #pragma unroll
                    for (int m = 1; m < 64; m <<= 1) acc += __shfl_xor(acc, m, 64);
                    if (laneL == 0)
                        stD(&dhb[growL], scale0 * tanhf(0.01f * (acc + bl[growL])));
                }
                ++R; publish(Sdh, blk, R, t);

                // ---- gather dh: thread t<64 waits on producer t, reads 4 floats ----
                if (t < 64) {
                    while (ldS(Sdh + t) != R) {}
                    __atomic_signal_fence(__ATOMIC_SEQ_CST);
                    #pragma unroll
                    for (int i = 0; i < 4; i++)
                        k_s[NSTATE + t * 4 + i] = ldD(dhb + t * 4 + i);
                }
                __syncthreads();
                for (int i = t; i < NX; i += BS) yn_s[i] += w * k_s[i];
            } // stages

            __syncthreads();
            for (int i = t; i < NX; i += BS) y_s[i] = yn_s[i];
            __syncthreads();
        } // substeps

        if (blk == 0) {
            if (t < NSTATE) out[(iv + 1) * NSTATE + t] = y_s[t];
            out[NT * NSTATE + (iv + 1) * NH + t] = y_s[NSTATE + t];
        }
    } // intervals
}

extern "C" void kernel_launch(void* const* d_in, const int* in_sizes, int n_in,
                              void* d_out, int out_size, void* d_ws, size_t ws_size,
                              hipStream_t stream) {
    const float* ts    = (const float*)d_in[0];
    const float* W0    = (const float*)d_in[1];
    const float* b0    = (const float*)d_in[2];
    const float* Wh    = (const float*)d_in[3];
    const float* bh    = (const float*)d_in[4];
    const float* Wl    = (const float*)d_in[5];
    const float* bl    = (const float*)d_in[6];
    const float* betaW = (const float*)d_in[7];
    const float* betab = (const float*)d_in[8];
    const float* hvec  = (const float*)d_in[9];
    const float* scale = (const float*)d_in[10];
    const float* y0log = (const float*)d_in[11];
    float* out = (float*)d_out;

    // ws layout: [0,256) SzA | [256,512) SzB | [512,768) Sdh (u32 x 64 each)
    //            [1024,5120) zA | [5120,9216) zB | [9216,10240) dhb
    uint*  SzA = (uint*)d_ws;
    uint*  SzB = (uint*)((char*)d_ws + 256);
    uint*  Sdh = (uint*)((char*)d_ws + 512);
    float* zA  = (float*)((char*)d_ws + 1024);
    float* zB  = (float*)((char*)d_ws + 5120);
    float* dhb = (float*)((char*)d_ws + 9216);

    // zero the summary words (round counter starts at 1; poison != any R)
    hipMemsetAsync(d_ws, 0, 1024, stream);
    hipLaunchKernelGGL(ode_kernel, dim3(NBLK), dim3(BS), 0, stream,
                       ts, W0, b0, Wh, bh, Wl, bl, betaW, betab, hvec, scale,
                       y0log, out, SzA, SzB, Sdh, zA, zB, dhb);
}

// Round 9
// 36062.991 us; speedup vs baseline: 1.3728x; 1.3728x over previous
//
#include <hip/hip_runtime.h>
#include <math.h>

#define NBLK   64
#define BS     256
#define NSTATE 17
#define NH     256
#define NX     273      // NH + NSTATE
#define WID    1024
#define NT     64
#define NSUB   8
#define ROWS_H (WID/NBLK)   // 16 rows/block, 1024-wide layers
#define ROWS_L (NH/NBLK)    // 4 rows/block, 256-wide output layer

typedef unsigned long long u64;

// Mailbox workspace: zmbA/zmbB = 64 consumers x 1024 u64 (512 KB each),
// dhmb = 64 x 256 u64 (128 KB). Tags are poison-safe (0xAAAAAAAA >> #rounds).
#define ZMB_WORDS  (64 * WID)
#define DHMB_WORDS (64 * NH)
#define WS_NEED    ((size_t)(2 * ZMB_WORDS + DHMB_WORDS) * 8)   // 1,179,648 B

__device__ __forceinline__ float softplus_f(float v) {
    return fmaxf(v, 0.f) + log1pf(expf(-fabsf(v)));
}

// Fused tag+payload word, RELAXED AGENT scope (proven r3 codegen).
__device__ __forceinline__ void st_tag(u64* p, float v, unsigned R) {
    u64 w = ((u64)R << 32) | (u64)__float_as_uint(v);
    __hip_atomic_store(p, w, __ATOMIC_RELAXED, __HIP_MEMORY_SCOPE_AGENT);
}
__device__ __forceinline__ u64 ld_tag(const u64* p) {
    return __hip_atomic_load(p, __ATOMIC_RELAXED, __HIP_MEMORY_SCOPE_AGENT);
}

// r3's proven poll sweep, but over THIS BLOCK'S PRIVATE mailbox: thread t
// owns words {t, t+256, t+512, t+768}; stride-1 LDS deposit (0 conflicts, r3).
__device__ __forceinline__ void poll_mb(const u64* __restrict__ mb, unsigned R,
                                        float* __restrict__ z_s, int t) {
    float v[4];
    unsigned done = 0;
    while (done != 0xFu) {
        #pragma unroll
        for (int i = 0; i < 4; i++) {
            if (!(done & (1u << i))) {
                u64 w = ld_tag(mb + t + i * 256);
                if ((unsigned)(w >> 32) == R) {
                    v[i] = __uint_as_float((unsigned)w);
                    done |= 1u << i;
                }
            }
        }
    }
    #pragma unroll
    for (int i = 0; i < 4; i++) z_s[t + i * 256] = v[i];
    __syncthreads();
}

// ======================================================================
// Path A: private-mailbox kernel
// ======================================================================
extern "C" __global__ __launch_bounds__(BS, 1) void ode_mb(
    const float* __restrict__ ts,   const float* __restrict__ W0,
    const float* __restrict__ b0,   const float* __restrict__ Wh,
    const float* __restrict__ bh,   const float* __restrict__ Wl,
    const float* __restrict__ bl,   const float* __restrict__ betaW,
    const float* __restrict__ betab,const float* __restrict__ hvec,
    const float* __restrict__ scale,const float* __restrict__ y0log,
    float* __restrict__ out, u64* zmbA, u64* zmbB, u64* dhmb)
{
    const int t   = threadIdx.x;
    const int blk = blockIdx.x;

    __shared__ float y_s[NX];
    __shared__ float yn_s[NX];
    __shared__ float x_s[NX];
    __shared__ float xm[NX];
    __shared__ float k_s[NX];
    __shared__ __align__(16) float z_s[WID];
    __shared__ float zloc[16];    // this block's 16 layer outputs (staging)
    __shared__ float dhloc[4];    // this block's 4 dh outputs
    __shared__ float red[4];
    __shared__ float dt_sh;

    const float scale0 = scale[0];
    const float betab0 = betab[0];
    unsigned R = 0;

    // my private inbound mailboxes
    u64* myZA = zmbA + (size_t)blk * WID;
    u64* myZB = zmbB + (size_t)blk * WID;
    u64* myDH = dhmb + (size_t)blk * NH;

    // fan-out targets for z legs: thread t -> consumer c, word offset j0..j0+3
    const int fc  = t >> 2;           // consumer 0..63
    const int fj0 = (t & 3) * 4;      // 4 consecutive of my 16 words

    // ---- y0 = [softmax(y0_log), hvec] ----
    if (t < NSTATE) {
        float m = -1e30f;
        for (int j = 0; j < NSTATE; j++) m = fmaxf(m, y0log[j]);
        float ssum = 0.f;
        for (int j = 0; j < NSTATE; j++) ssum += expf(y0log[j] - m);
        y_s[t] = expf(y0log[t] - m) / ssum;
    }
    y_s[NSTATE + t] = hvec[t];
    __syncthreads();

    if (blk == 0) {
        if (t < NSTATE) out[t] = y_s[t];
        out[NT * NSTATE + t] = y_s[NSTATE + t];
    }

    const float c_xi = 13.f / 12.f, c_mu = 0.041f / 12.f, c_sig = 91.f / 12.f,
                c_nu = 36.f / 12.f, c_gam = 1.8f / 12.f;

    const int laneH = t & 15, rowq = t >> 4;
    const int growH = blk * ROWS_H + rowq;
    const int laneL = t & 63, rquad = t >> 6;
    const int growL = blk * ROWS_L + rquad;

    for (int iv = 0; iv < NT - 1; iv++) {
        if (t == 0) dt_sh = (ts[iv + 1] - ts[iv]) * (1.f / NSUB);
        __syncthreads();
        const float dt = dt_sh;

        for (int sub = 0; sub < NSUB; sub++) {
            for (int i = t; i < NX; i += BS) yn_s[i] = y_s[i];

            for (int s = 0; s < 4; s++) {
                const float a = (s == 0) ? 0.f : ((s == 3) ? 1.f : 0.5f);
                const float w = ((s == 0) || (s == 3)) ? dt * (1.f / 6.f) : dt * (1.f / 3.f);

                // ---- stage input x = y + a*dt*k_prev ----
                if (s == 0) { for (int i = t; i < NX; i += BS) x_s[i] = y_s[i]; }
                else        { for (int i = t; i < NX; i += BS) x_s[i] = y_s[i] + a * dt * k_s[i]; }
                __syncthreads();

                // ---- MLP input reorder + beta head partial ----
                xm[t] = x_s[NSTATE + t];
                if (t < NSTATE) xm[NH + t] = x_s[t];
                float p = betaW[t] * x_s[NSTATE + t];
                #pragma unroll
                for (int m = 1; m < 64; m <<= 1) p += __shfl_xor(p, m, 64);
                if ((t & 63) == 0) red[t >> 6] = p;
                __syncthreads();

                // ---- dstate (redundant per block, thread 0) ----
                if (t == 0) {
                    float sd  = red[0] + red[1] + red[2] + red[3] + betab0;
                    float bb1 = 8.f / (1.f + expf(-sd)) + 25.f;
                    float bb2 = 0.5f * bb1, bb3 = 0.35f * bb1, bb4 = 0.25f * bb1;
                    float M  = x_s[0],  S1 = x_s[1],  E1 = x_s[2],  E2 = x_s[3];
                    float E3 = x_s[4],  E4 = x_s[5],  I1 = x_s[6],  I2 = x_s[7];
                    float I3 = x_s[8],  I4 = x_s[9],  R1 = x_s[10], R2 = x_s[11];
                    float R3 = x_s[12], R4 = x_s[13], S2 = x_s[14], S3 = x_s[15];
                    float S4 = x_s[16];
                    float I = I1 + I2 + I3 + I4, Rs = R1 + R2 + R3 + R4;
                    k_s[0]  = Rs * c_mu - (c_xi + c_mu) * M;
                    k_s[1]  = c_mu * (1.f - Rs) + c_xi * M - c_mu * S1 - bb1 * I * S1;
                    k_s[2]  = bb1 * I * S1 - (c_mu + c_sig) * E1;
                    k_s[3]  = bb2 * I * S2 - (c_mu + c_sig) * E2;
                    k_s[4]  = bb3 * I * S3 - (c_mu + c_sig) * E3;
                    k_s[5]  = bb4 * I * S4 - (c_mu + c_sig) * E4;
                    k_s[6]  = c_sig * E1 - (c_nu + c_mu) * I1;
                    k_s[7]  = c_sig * E2 - (c_nu + c_mu) * I2;
                    k_s[8]  = c_sig * E3 - (c_nu + c_mu) * I3;
                    k_s[9]  = c_sig * E4 - (c_nu + c_mu) * I4;
                    k_s[10] = c_nu * I1 - (c_mu + c_gam) * R1;
                    k_s[11] = c_nu * I2 - (c_mu + c_gam) * R2;
                    k_s[12] = c_nu * I3 - (c_mu + c_gam) * R3;
                    k_s[13] = c_nu * I4 - (c_mu + c_gam) * R4;
                    k_s[14] = c_gam * R1 - c_mu * S2 - bb2 * I * S2;
                    k_s[15] = c_gam * R2 - c_mu * S3 - bb3 * I * S3;
                    k_s[16] = c_gam * (R3 + R4) - c_mu * S4 - bb4 * I * S4;
                }
                __syncthreads();

                // ---- L0: 16 rows/block -> stage to zloc, fan out to zmbA ----
                {
                    const float* wr = W0 + (size_t)growH * NX;
                    float acc = 0.f;
                    for (int c = laneH; c < NX; c += 16) acc += wr[c] * xm[c];
                    #pragma unroll
                    for (int m = 1; m < 16; m <<= 1) acc += __shfl_xor(acc, m, 16);
                    if (laneH == 0) zloc[rowq] = softplus_f(acc + b0[growH]);
                }
                __syncthreads();
                ++R;
                {
                    u64* dst = zmbA + (size_t)fc * WID + blk * 16 + fj0;
                    #pragma unroll
                    for (int i = 0; i < 4; i++) st_tag(dst + i, zloc[fj0 + i], R);
                }

                // ---- hidden layers 1..3; weight prefetch before poll ----
                for (int l = 0; l < 3; l++) {
                    const u64* myIn = (l == 1) ? myZB : myZA;
                    u64*       obuf = (l == 1) ? zmbA : zmbB;

                    const float* wr = Wh + (size_t)l * WID * WID + (size_t)growH * WID;
                    float4 wv[16];
                    #pragma unroll
                    for (int i = 0; i < 16; i++)
                        wv[i] = *(const float4*)(wr + (laneH * 4 + i * 64));

                    poll_mb(myIn, R, z_s, t);

                    float acc = 0.f;
                    #pragma unroll
                    for (int i = 0; i < 16; i++) {
                        float4 zv = *(const float4*)(z_s + (laneH * 4 + i * 64));
                        acc += wv[i].x * zv.x + wv[i].y * zv.y + wv[i].z * zv.z + wv[i].w * zv.w;
                    }
                    #pragma unroll
                    for (int m = 1; m < 16; m <<= 1) acc += __shfl_xor(acc, m, 16);
                    if (laneH == 0) zloc[rowq] = softplus_f(acc + bh[l * WID + growH]);
                    __syncthreads();
                    ++R;
                    {
                        u64* dst = obuf + (size_t)fc * WID + blk * 16 + fj0;
                        #pragma unroll
                        for (int i = 0; i < 4; i++) st_tag(dst + i, zloc[fj0 + i], R);
                    }
                }

                // ---- Wl: 4 rows/block; tanh epilogue; fan out to dhmb ----
                {
                    const float* wr = Wl + (size_t)growL * WID;
                    float4 wv[4];
                    #pragma unroll
                    for (int i = 0; i < 4; i++)
                        wv[i] = *(const float4*)(wr + (laneL * 4 + i * 256));

                    poll_mb(myZB, R, z_s, t);   // h3 lives in zmbB

                    float acc = 0.f;
                    #pragma unroll
                    for (int i = 0; i < 4; i++) {
                        float4 zv = *(const float4*)(z_s + (laneL * 4 + i * 256));
                        acc += wv[i].x * zv.x + wv[i].y * zv.y + wv[i].z * zv.z + wv[i].w * zv.w;
                    }
                    #pragma unroll
                    for (int m = 1; m < 64; m <<= 1) acc += __shfl_xor(acc, m, 64);
                    if (laneL == 0) dhloc[rquad] = scale0 * tanhf(0.01f * (acc + bl[growL]));
                }
                __syncthreads();
                ++R;
                {   // thread t -> consumer c=t>>2, word blk*4 + (t&3)
                    u64* dst = dhmb + (size_t)(t >> 2) * NH + blk * 4 + (t & 3);
                    st_tag(dst, dhloc[t & 3], R);
                }

                // ---- gather dh from MY dh mailbox: 1 word/thread, private lines ----
                {
                    u64 wv;
                    do { wv = ld_tag(myDH + t); } while ((unsigned)(wv >> 32) != R);
                    k_s[NSTATE + t] = __uint_as_float((unsigned)wv);
                }
                __syncthreads();
                for (int i = t; i < NX; i += BS) yn_s[i] += w * k_s[i];
            } // stages

            __syncthreads();
            for (int i = t; i < NX; i += BS) y_s[i] = yn_s[i];
            __syncthreads();
        } // substeps

        if (blk == 0) {
            if (t < NSTATE) out[(iv + 1) * NSTATE + t] = y_s[t];
            out[NT * NSTATE + (iv + 1) * NH + t] = y_s[NSTATE + t];
        }
    } // intervals
}

// ======================================================================
// Path B: r3 kernel verbatim (proven 34 ms) — used when ws is too small.
// ======================================================================
__device__ __forceinline__ void poll_z3(const u64* __restrict__ buf, unsigned R,
                                        float* __restrict__ z_s, int t) {
    float v[4];
    unsigned done = 0;
    while (done != 0xFu) {
        #pragma unroll
        for (int i = 0; i < 4; i++) {
            if (!(done & (1u << i))) {
                u64 w = ld_tag(buf + t + i * 256);
                if ((unsigned)(w >> 32) == R) {
                    v[i] = __uint_as_float((unsigned)w);
                    done |= 1u << i;
                }
            }
        }
    }
    #pragma unroll
    for (int i = 0; i < 4; i++) z_s[t + i * 256] = v[i];
    __syncthreads();
}

extern "C" __global__ __launch_bounds__(BS, 1) void ode_fab(
    const float* __restrict__ ts,   const float* __restrict__ W0,
    const float* __restrict__ b0,   const float* __restrict__ Wh,
    const float* __restrict__ bh,   const float* __restrict__ Wl,
    const float* __restrict__ bl,   const float* __restrict__ betaW,
    const float* __restrict__ betab,const float* __restrict__ hvec,
    const float* __restrict__ scale,const float* __restrict__ y0log,
    float* __restrict__ out, u64* zA, u64* zB, u64* dhb)
{
    const int t   = threadIdx.x;
    const int blk = blockIdx.x;

    __shared__ float y_s[NX], yn_s[NX], x_s[NX], xm[NX], k_s[NX];
    __shared__ __align__(16) float z_s[WID];
    __shared__ float red[4];
    __shared__ float dt_sh;

    const float scale0 = scale[0];
    const float betab0 = betab[0];
    unsigned R = 0;

    if (t < NSTATE) {
        float m = -1e30f;
        for (int j = 0; j < NSTATE; j++) m = fmaxf(m, y0log[j]);
        float ssum = 0.f;
        for (int j = 0; j < NSTATE; j++) ssum += expf(y0log[j] - m);
        y_s[t] = expf(y0log[t] - m) / ssum;
    }
    y_s[NSTATE + t] = hvec[t];
    __syncthreads();

    if (blk == 0) {
        if (t < NSTATE) out[t] = y_s[t];
        out[NT * NSTATE + t] = y_s[NSTATE + t];
    }

    const float c_xi = 13.f / 12.f, c_mu = 0.041f / 12.f, c_sig = 91.f / 12.f,
                c_nu = 36.f / 12.f, c_gam = 1.8f / 12.f;

    const int laneH = t & 15;
    const int growH = blk * ROWS_H + (t >> 4);
    const int laneL = t & 63;
    const int growL = blk * ROWS_L + (t >> 6);

    for (int iv = 0; iv < NT - 1; iv++) {
        if (t == 0) dt_sh = (ts[iv + 1] - ts[iv]) * (1.f / NSUB);
        __syncthreads();
        const float dt = dt_sh;

        for (int sub = 0; sub < NSUB; sub++) {
            for (int i = t; i < NX; i += BS) yn_s[i] = y_s[i];

            for (int s = 0; s < 4; s++) {
                const float a = (s == 0) ? 0.f : ((s == 3) ? 1.f : 0.5f);
                const float w = ((s == 0) || (s == 3)) ? dt * (1.f / 6.f) : dt * (1.f / 3.f);

                if (s == 0) { for (int i = t; i < NX; i += BS) x_s[i] = y_s[i]; }
                else        { for (int i = t; i < NX; i += BS) x_s[i] = y_s[i] + a * dt * k_s[i]; }
                __syncthreads();

                xm[t] = x_s[NSTATE + t];
                if (t < NSTATE) xm[NH + t] = x_s[t];
                float p = betaW[t] * x_s[NSTATE + t];
                #pragma unroll
                for (int m = 1; m < 64; m <<= 1) p += __shfl_xor(p, m, 64);
                if ((t & 63) == 0) red[t >> 6] = p;
                __syncthreads();

                if (t == 0) {
                    float sd  = red[0] + red[1] + red[2] + red[3] + betab0;
                    float bb1 = 8.f / (1.f + expf(-sd)) + 25.f;
                    float bb2 = 0.5f * bb1, bb3 = 0.35f * bb1, bb4 = 0.25f * bb1;
                    float M  = x_s[0],  S1 = x_s[1],  E1 = x_s[2],  E2 = x_s[3];
                    float E3 = x_s[4],  E4 = x_s[5],  I1 = x_s[6],  I2 = x_s[7];
                    float I3 = x_s[8],  I4 = x_s[9],  R1 = x_s[10], R2 = x_s[11];
                    float R3 = x_s[12], R4 = x_s[13], S2 = x_s[14], S3 = x_s[15];
                    float S4 = x_s[16];
                    float I = I1 + I2 + I3 + I4, Rs = R1 + R2 + R3 + R4;
                    k_s[0]  = Rs * c_mu - (c_xi + c_mu) * M;
                    k_s[1]  = c_mu * (1.f - Rs) + c_xi * M - c_mu * S1 - bb1 * I * S1;
                    k_s[2]  = bb1 * I * S1 - (c_mu + c_sig) * E1;
                    k_s[3]  = bb2 * I * S2 - (c_mu + c_sig) * E2;
                    k_s[4]  = bb3 * I * S3 - (c_mu + c_sig) * E3;
                    k_s[5]  = bb4 * I * S4 - (c_mu + c_sig) * E4;
                    k_s[6]  = c_sig * E1 - (c_nu + c_mu) * I1;
                    k_s[7]  = c_sig * E2 - (c_nu + c_mu) * I2;
                    k_s[8]  = c_sig * E3 - (c_nu + c_mu) * I3;
                    k_s[9]  = c_sig * E4 - (c_nu + c_mu) * I4;
                    k_s[10] = c_nu * I1 - (c_mu + c_gam) * R1;
                    k_s[11] = c_nu * I2 - (c_mu + c_gam) * R2;
                    k_s[12] = c_nu * I3 - (c_mu + c_gam) * R3;
                    k_s[13] = c_nu * I4 - (c_mu + c_gam) * R4;
                    k_s[14] = c_gam * R1 - c_mu * S2 - bb2 * I * S2;
                    k_s[15] = c_gam * R2 - c_mu * S3 - bb3 * I * S3;
                    k_s[16] = c_gam * (R3 + R4) - c_mu * S4 - bb4 * I * S4;
                }
                __syncthreads();

                {
                    const float* wr = W0 + (size_t)growH * NX;
                    float acc = 0.f;
                    for (int c = laneH; c < NX; c += 16) acc += wr[c] * xm[c];
                    #pragma unroll
                    for (int m = 1; m < 16; m <<= 1) acc += __shfl_xor(acc, m, 16);
                    ++R;
                    if (laneH == 0) st_tag(&zA[growH], softplus_f(acc + b0[growH]), R);
                }

                u64* zp[2] = { zA, zB };
                int cur = 0;
                for (int l = 0; l < 3; l++) {
                    const u64* zin = zp[cur];
                    u64* zout = zp[cur ^ 1];
                    const float* wr = Wh + (size_t)l * WID * WID + (size_t)growH * WID;
                    float4 wv[16];
                    #pragma unroll
                    for (int i = 0; i < 16; i++)
                        wv[i] = *(const float4*)(wr + (laneH * 4 + i * 64));

                    poll_z3(zin, R, z_s, t);

                    float acc = 0.f;
                    #pragma unroll
                    for (int i = 0; i < 16; i++) {
                        float4 zv = *(const float4*)(z_s + (laneH * 4 + i * 64));
                        acc += wv[i].x * zv.x + wv[i].y * zv.y + wv[i].z * zv.z + wv[i].w * zv.w;
                    }
                    #pragma unroll
                    for (int m = 1; m < 16; m <<= 1) acc += __shfl_xor(acc, m, 16);
                    ++R;
                    if (laneH == 0)
                        st_tag(&zout[growH], softplus_f(acc + bh[l * WID + growH]), R);
                    cur ^= 1;
                }

                {
                    const u64* zin = zp[cur];
                    const float* wr = Wl + (size_t)growL * WID;
                    float4 wv[4];
                    #pragma unroll
                    for (int i = 0; i < 4; i++)
                        wv[i] = *(const float4*)(wr + (laneL * 4 + i * 256));

                    poll_z3(zin, R, z_s, t);

                    float acc = 0.f;
                    #pragma unroll
                    for (int i = 0; i < 4; i++) {
                        float4 zv = *(const float4*)(z_s + (laneL * 4 + i * 256));
                        acc += wv[i].x * zv.x + wv[i].y * zv.y + wv[i].z * zv.z + wv[i].w * zv.w;
                    }
                    #pragma unroll
                    for (int m = 1; m < 64; m <<= 1) acc += __shfl_xor(acc, m, 64);
                    ++R;
                    if (laneL == 0)
                        st_tag(&dhb[growL], scale0 * tanhf(0.01f * (acc + bl[growL])), R);
                }

                {
                    u64 wv;
                    do { wv = ld_tag(dhb + t); } while ((unsigned)(wv >> 32) != R);
                    k_s[NSTATE + t] = __uint_as_float((unsigned)wv);
                }
                __syncthreads();
                for (int i = t; i < NX; i += BS) yn_s[i] += w * k_s[i];
            } // stages

            __syncthreads();
            for (int i = t; i < NX; i += BS) y_s[i] = yn_s[i];
            __syncthreads();
        } // substeps

        if (blk == 0) {
            if (t < NSTATE) out[(iv + 1) * NSTATE + t] = y_s[t];
            out[NT * NSTATE + (iv + 1) * NH + t] = y_s[NSTATE + t];
        }
    } // intervals
}

extern "C" void kernel_launch(void* const* d_in, const int* in_sizes, int n_in,
                              void* d_out, int out_size, void* d_ws, size_t ws_size,
                              hipStream_t stream) {
    const float* ts    = (const float*)d_in[0];
    const float* W0    = (const float*)d_in[1];
    const float* b0    = (const float*)d_in[2];
    const float* Wh    = (const float*)d_in[3];
    const float* bh    = (const float*)d_in[4];
    const float* Wl    = (const float*)d_in[5];
    const float* bl    = (const float*)d_in[6];
    const float* betaW = (const float*)d_in[7];
    const float* betab = (const float*)d_in[8];
    const float* hvec  = (const float*)d_in[9];
    const float* scale = (const float*)d_in[10];
    const float* y0log = (const float*)d_in[11];
    float* out = (float*)d_out;

    if (ws_size >= WS_NEED) {
        // Mailbox path. No memset needed: poison tag 0xAAAAAAAA != any R
        // (total rounds 10080), and R restarts at 1 every launch.
        u64* zmbA = (u64*)d_ws;
        u64* zmbB = zmbA + ZMB_WORDS;
        u64* dhmb = zmbB + ZMB_WORDS;
        hipLaunchKernelGGL(ode_mb, dim3(NBLK), dim3(BS), 0, stream,
                           ts, W0, b0, Wh, bh, Wl, bl, betaW, betab, hvec, scale,
                           y0log, out, zmbA, zmbB, dhmb);
    } else {
        u64* zA  = (u64*)d_ws;
        u64* zB  = (u64*)((char*)d_ws + 8192);
        u64* dhb = (u64*)((char*)d_ws + 16384);
        hipMemsetAsync(d_ws, 0, 18432, stream);
        hipLaunchKernelGGL(ode_fab, dim3(NBLK), dim3(BS), 0, stream,
                           ts, W0, b0, Wh, bh, Wl, bl, betaW, betab, hvec, scale,
                           y0log, out, zA, zB, dhb);
    }
}